// Round 14
// baseline (238.134 us; speedup 1.0000x reference)
//
#include <hip/hip_runtime.h>
#include <hip/hip_bf16.h>
#include <math.h>

#define B_ 4
#define L_ 512
#define V_ 4
#define D_ 256
#define DS_ 16
#define DI_ 512
#define DTR_ 16
#define ML (B_*L_)              /* 2048 rows per view */
#define NC_ 32                  /* scan chunks */
#define CL_ 16                  /* steps per chunk = L_/NC_ */

/* workspace layout (floats) — ws >= 268MB, everything DEDICATED (no aliasing).
   ERRATUM R13: SZ_WIN/SZ_WOUT were half-sized (missed that hi+lo = 2N ushorts = N floats);
   w_out's split overwrote w_in's lo plane -> absmax 3.6e4. Fixed: full N floats each. */
#define OFF_XZ    0L
#define SZ_XZ     ((long)V_*ML*2*DI_)        /* 8,388,608 */
#define OFF_XC    (OFF_XZ + SZ_XZ)
#define SZ_XC     ((long)V_*ML*DI_)          /* 4,194,304 */
#define OFF_XLN   (OFF_XC + SZ_XC)
#define SZ_XLN    ((long)V_*ML*D_)           /* hi+lo ushort planes */
#define OFF_WIN   (OFF_XLN + SZ_XLN)
#define SZ_WIN    ((long)V_*(2*DI_)*D_)      /* hi+lo ushort planes (FIXED) */
#define OFF_WOUT  (OFF_WIN + SZ_WIN)
#define SZ_WOUT   ((long)V_*D_*DI_)          /* hi+lo ushort planes (FIXED) */
#define OFF_Y     (OFF_WOUT + SZ_WOUT)
#define SZ_Y      ((long)V_*ML*DI_)          /* yh+yl ushort planes */
#define OFF_P     (OFF_Y + SZ_Y)
#define SZ_P      ((long)V_*ML*192)          /* nt48 split-K partials, stride 192 */
#define OFF_HB    (OFF_P + SZ_P)
#define SZ_HB     ((long)V_*B_*NC_*DI_*16)
#define OFF_SDEL  (OFF_HB + SZ_HB)
#define SZ_SDEL   ((long)V_*B_*NC_*DI_)

typedef short short8_t __attribute__((ext_vector_type(8)));
typedef float f32x4_t  __attribute__((ext_vector_type(4)));

#define LOG2E 1.44269504088896341f
#define LN2   0.69314718055994531f

__device__ __forceinline__ float exp2_fast(float x) { return __builtin_amdgcn_exp2f(x); }
__device__ __forceinline__ float softplus_fast(float x) {
    const float t = __builtin_amdgcn_exp2f(x * LOG2E);
    const float r = __builtin_amdgcn_logf(1.f + t) * LN2;
    return x > 20.f ? x : r;
}
__device__ __forceinline__ float silu_fast(float z) {
    const float t = __builtin_amdgcn_exp2f(-LOG2E * z);
    return z * __builtin_amdgcn_rcpf(1.f + t);
}
__device__ __forceinline__ ushort f2bf(float f) {
    uint u = __float_as_uint(f);
    return (ushort)((u + 0x7fffu + ((u >> 16) & 1u)) >> 16);
}
__device__ __forceinline__ float bf2f(ushort h) { return __uint_as_float(((uint)h) << 16); }

/* ---------------- weight hi/lo split ---------------- */
__global__ __launch_bounds__(256) void split_w(const float* __restrict__ in,
                                               ushort* __restrict__ oh,
                                               ushort* __restrict__ ol, int n4)
{
    const int i = blockIdx.x*256 + threadIdx.x;
    if (i >= n4) return;
    const float4 f = ((const float4*)in)[i];
    const ushort h0=f2bf(f.x), h1=f2bf(f.y), h2=f2bf(f.z), h3=f2bf(f.w);
    ((short4*)oh)[i] = make_short4((short)h0,(short)h1,(short)h2,(short)h3);
    ((short4*)ol)[i] = make_short4((short)f2bf(f.x-bf2f(h0)), (short)f2bf(f.y-bf2f(h1)),
                                   (short)f2bf(f.z-bf2f(h2)), (short)f2bf(f.w-bf2f(h3)));
}

/* ---------------- LayerNorm fused with hi/lo split ---------------- */
__global__ __launch_bounds__(256) void ln_split(const float* __restrict__ x,
                                                const float* __restrict__ g,
                                                const float* __restrict__ bta,
                                                ushort* __restrict__ xh,
                                                ushort* __restrict__ xl)
{
    const int m = blockIdx.x;
    const int v = blockIdx.y;
    const int d = threadIdx.x;
    const float val = x[((long)m*V_ + v)*D_ + d];
    float s = val, sq = val*val;
#pragma unroll
    for (int off = 32; off >= 1; off >>= 1) {
        s  += __shfl_xor(s, off);
        sq += __shfl_xor(sq, off);
    }
    __shared__ float ws[4], wq[4];
    if ((threadIdx.x & 63) == 0) { ws[threadIdx.x >> 6] = s; wq[threadIdx.x >> 6] = sq; }
    __syncthreads();
    s  = ws[0]+ws[1]+ws[2]+ws[3];
    sq = wq[0]+wq[1]+wq[2]+wq[3];
    const float mu  = s * (1.f/D_);
    const float var = sq * (1.f/D_) - mu*mu;
    const float inv = rsqrtf(var + 1e-5f);
    const float r = (val - mu)*inv*g[v*D_+d] + bta[v*D_+d];
    const ushort h = f2bf(r);
    const long idx = ((long)v*ML + m)*D_ + d;
    xh[idx] = h;
    xl[idx] = f2bf(r - bf2f(h));
}

/* ---------------- split-bf16 MFMA GEMM (in): NO LDS — direct per-lane fragment loads.
   Every 16x16x32 fragment is a contiguous 16B chunk at row*K + k0 + fg*8; a wave's 64
   lanes cover 16 full 64B lines per load. Zero barriers; reuse via L1/L2. ---------------- */
__global__ __launch_bounds__(256) void mfma_gemm_in(
    const ushort* __restrict__ Ah, const ushort* __restrict__ Al,
    const ushort* __restrict__ Bh, const ushort* __restrict__ Bl,
    float* __restrict__ C)
{
    const int v = blockIdx.z;
    const int bm = blockIdx.y*128, bn = blockIdx.x*128;
    const int lane = threadIdx.x & 63, w = threadIdx.x >> 6;
    const int wr = w >> 1, wc = w & 1;
    const int fm = lane & 15, fg = lane >> 4;
    const long Ab = (long)v*ML*D_       + (long)(bm + wr*64 + fm)*D_ + fg*8;
    const long Bb = (long)v*(2*DI_)*D_  + (long)(bn + wc*64 + fm)*D_ + fg*8;
    C += (long)v*ML*(2*DI_);

    f32x4_t acc[4][4];
#pragma unroll
    for (int i=0;i<4;++i)
#pragma unroll
        for (int j=0;j<4;++j)
#pragma unroll
            for (int k=0;k<4;++k) acc[i][j][k]=0.f;

#pragma unroll 2
    for (int k0 = 0; k0 < D_; k0 += 32) {
        short8_t ah[4], al[4], bh[4], bl[4];
#pragma unroll
        for (int i = 0; i < 4; ++i) {
            ah[i] = *(const short8_t*)(Ah + Ab + (long)i*16*D_ + k0);
            al[i] = *(const short8_t*)(Al + Ab + (long)i*16*D_ + k0);
            bh[i] = *(const short8_t*)(Bh + Bb + (long)i*16*D_ + k0);
            bl[i] = *(const short8_t*)(Bl + Bb + (long)i*16*D_ + k0);
        }
#pragma unroll
        for (int i=0;i<4;++i)
#pragma unroll
            for (int j=0;j<4;++j) {
                acc[i][j] = __builtin_amdgcn_mfma_f32_16x16x32_bf16(ah[i], bh[j], acc[i][j], 0,0,0);
                acc[i][j] = __builtin_amdgcn_mfma_f32_16x16x32_bf16(ah[i], bl[j], acc[i][j], 0,0,0);
                acc[i][j] = __builtin_amdgcn_mfma_f32_16x16x32_bf16(al[i], bh[j], acc[i][j], 0,0,0);
            }
    }
#pragma unroll
    for (int i=0;i<4;++i)
#pragma unroll
        for (int j4=0;j4<4;++j4) {
            const int row = bm + wr*64 + i*16 + fg*4 + j4;
            float* cr = C + (long)row*(2*DI_) + bn + wc*64 + fm;
#pragma unroll
            for (int j=0;j<4;++j) cr[j*16] = acc[i][j][j4];
        }
}

/* ---------------- split-bf16 MFMA GEMM (out): same direct-load structure.
   A = yh/yl bf16 planes; 64x128 block (2x2 waves of 32x64) -> 256 blocks. ---------------- */
__global__ __launch_bounds__(256) void mfma_gemm_out(
    const ushort* __restrict__ Ahp, const ushort* __restrict__ Alp,
    const ushort* __restrict__ Bh,  const ushort* __restrict__ Bl,
    float* __restrict__ Cout)
{
    const int v = blockIdx.z;
    const int bm = blockIdx.y*64, bn = blockIdx.x*128;
    const int lane = threadIdx.x & 63, w = threadIdx.x >> 6;
    const int wr = w >> 1, wc = w & 1;
    const int fm = lane & 15, fg = lane >> 4;
    const long Ab = (long)v*ML*DI_ + (long)(bm + wr*32 + fm)*DI_ + fg*8;
    const long Bb = (long)v*D_*DI_ + (long)(bn + wc*64 + fm)*DI_ + fg*8;

    f32x4_t acc[2][4];
#pragma unroll
    for (int i=0;i<2;++i)
#pragma unroll
        for (int j=0;j<4;++j)
#pragma unroll
            for (int k=0;k<4;++k) acc[i][j][k]=0.f;

#pragma unroll 2
    for (int k0 = 0; k0 < DI_; k0 += 32) {
        short8_t ah[2], al[2], bh[4], bl[4];
#pragma unroll
        for (int i = 0; i < 2; ++i) {
            ah[i] = *(const short8_t*)(Ahp + Ab + (long)i*16*DI_ + k0);
            al[i] = *(const short8_t*)(Alp + Ab + (long)i*16*DI_ + k0);
        }
#pragma unroll
        for (int j = 0; j < 4; ++j) {
            bh[j] = *(const short8_t*)(Bh + Bb + (long)j*16*DI_ + k0);
            bl[j] = *(const short8_t*)(Bl + Bb + (long)j*16*DI_ + k0);
        }
#pragma unroll
        for (int i=0;i<2;++i)
#pragma unroll
            for (int j=0;j<4;++j) {
                acc[i][j] = __builtin_amdgcn_mfma_f32_16x16x32_bf16(ah[i], bh[j], acc[i][j], 0,0,0);
                acc[i][j] = __builtin_amdgcn_mfma_f32_16x16x32_bf16(ah[i], bl[j], acc[i][j], 0,0,0);
                acc[i][j] = __builtin_amdgcn_mfma_f32_16x16x32_bf16(al[i], bh[j], acc[i][j], 0,0,0);
            }
    }
    const long TOT = (long)ML * V_ * D_;
#pragma unroll
    for (int i=0;i<2;++i)
#pragma unroll
        for (int j4=0;j4<4;++j4) {
            const int row = bm + wr*32 + i*16 + fg*4 + j4;
#pragma unroll
            for (int j=0;j<4;++j) {
                const int col = bn + wc*64 + j*16 + fm;
                const long base = ((long)row*V_ + v)*D_ + col;
                const float val = acc[i][j][j4];
                Cout[base]       = val;
                Cout[base + TOT] = val;
            }
        }
}

/* ---------------- depthwise causal conv (DCONV=4) + bias + SiLU ---------------- */
__global__ __launch_bounds__(512) void conv_silu(const float* __restrict__ xz,
                                                 const float* __restrict__ cw,
                                                 const float* __restrict__ cb,
                                                 float* __restrict__ xc)
{
    const int m = blockIdx.x;
    const int v = blockIdx.y;
    const int c = threadIdx.x;
    const int l = m & 511;
    const float* xzv = xz + (long)v*ML*2*DI_;
    const float4 w4 = *(const float4*)&cw[((long)v*DI_ + c)*4];
    const float w[4] = {w4.x, w4.y, w4.z, w4.w};
    float acc = cb[v*DI_ + c];
#pragma unroll
    for (int k = 0; k < 4; ++k) {
        const int lp = l - 3 + k;
        if (lp >= 0) acc = fmaf(xzv[(long)(m - 3 + k)*(2*DI_) + c], w[k], acc);
    }
    xc[((long)v*ML + m)*DI_ + c] = silu_fast(acc);
}

/* ---------------- gemm_nt48 split-K: partials -> dedicated P [V][ML][192] ---------------- */
__global__ __launch_bounds__(256) void gemm_nt48_sk(const float* __restrict__ A,
                                                    const float* __restrict__ Bm,
                                                    float* __restrict__ P)
{
    const int v = blockIdx.z;
    const int ks = blockIdx.y;
    A  += (long)v * ((long)ML*DI_);
    Bm += (long)v * ((long)48*DI_);
    P  += (long)v * ((long)ML*192);
    __shared__ float As[16][68];
    __shared__ float Bs[16][48];
    const int tid = threadIdx.x;
    const int tx = tid & 15, ty = tid >> 4;
    const int bm = blockIdx.x * 64;
    const int lr = tid >> 2;
    const int lk = (tid & 3) * 4;
    const float* Ag = A + (long)(bm + lr)*DI_ + lk;
    float acc[4][3] = {};
    for (int k0 = ks*128; k0 < ks*128 + 128; k0 += 16) {
        const float4 av = *(const float4*)(Ag + k0);
        float4 bv = {0,0,0,0};
        if (tid < 192) bv = *(const float4*)(Bm + (long)(tid >> 2)*DI_ + k0 + (tid & 3)*4);
        __syncthreads();
        As[lk+0][lr]=av.x; As[lk+1][lr]=av.y; As[lk+2][lr]=av.z; As[lk+3][lr]=av.w;
        if (tid < 192) {
            const int br = tid >> 2, bk = (tid & 3)*4;
            Bs[bk+0][br]=bv.x; Bs[bk+1][br]=bv.y; Bs[bk+2][br]=bv.z; Bs[bk+3][br]=bv.w;
        }
        __syncthreads();
#pragma unroll
        for (int kk = 0; kk < 16; ++kk) {
            const float4 a = *(const float4*)&As[kk][ty*4];
            const float b0 = Bs[kk][tx*3+0], b1 = Bs[kk][tx*3+1], b2 = Bs[kk][tx*3+2];
            acc[0][0]=fmaf(a.x,b0,acc[0][0]); acc[0][1]=fmaf(a.x,b1,acc[0][1]); acc[0][2]=fmaf(a.x,b2,acc[0][2]);
            acc[1][0]=fmaf(a.y,b0,acc[1][0]); acc[1][1]=fmaf(a.y,b1,acc[1][1]); acc[1][2]=fmaf(a.y,b2,acc[1][2]);
            acc[2][0]=fmaf(a.z,b0,acc[2][0]); acc[2][1]=fmaf(a.z,b1,acc[2][1]); acc[2][2]=fmaf(a.z,b2,acc[2][2]);
            acc[3][0]=fmaf(a.w,b0,acc[3][0]); acc[3][1]=fmaf(a.w,b1,acc[3][1]); acc[3][2]=fmaf(a.w,b2,acc[3][2]);
        }
    }
#pragma unroll
    for (int i = 0; i < 4; ++i)
#pragma unroll
        for (int j = 0; j < 3; ++j)
            P[(long)(bm + ty*4 + i)*192 + ks*48 + tx*3 + j] = acc[i][j];
}

/* ================= chunked parallel scan, delta fused, fast-math.
   sX staged by summing the 4 split-K partials directly (reduce48 eliminated). ========== */
__global__ __launch_bounds__(256) void scanA(const float* __restrict__ xcin,
                                             const float* __restrict__ part,
                                             const float* __restrict__ A_log,
                                             const float* __restrict__ wdt,
                                             const float* __restrict__ bdt,
                                             float* __restrict__ hbuf,
                                             float* __restrict__ sdel)
{
    const int c = blockIdx.x >> 1, half = blockIdx.x & 1;
    const int b = blockIdx.y, v = blockIdx.z;
    const int d = half*256 + threadIdx.x;
    const long rowbase = (long)v*ML + (long)b*L_ + (long)c*CL_;
    const float* xcv = xcin + rowbase*DI_;
    const float* pv  = part + rowbase*192;

    __shared__ float sX[CL_*48];
    for (int t = threadIdx.x; t < CL_*48; t += 256) {
        const int row = t/48, j = t - row*48;
        const float* pr = pv + (long)row*192 + j;
        sX[t] = (pr[0] + pr[48]) + (pr[96] + pr[144]);
    }

    float a2[16];
#pragma unroll
    for (int n = 0; n < 16; ++n)
        a2[n] = -exp2_fast(A_log[((long)v*DI_ + d)*DS_ + n] * LOG2E) * LOG2E;
    float wreg[16];
    {
        const float* wp = wdt + ((long)v*DI_ + d)*DTR_;
#pragma unroll
        for (int r = 0; r < 16; r += 4) {
            const float4 t4 = *(const float4*)(wp + r);
            wreg[r]=t4.x; wreg[r+1]=t4.y; wreg[r+2]=t4.z; wreg[r+3]=t4.w;
        }
    }
    const float bias = bdt[(long)v*DI_ + d];
    float h[16];
#pragma unroll
    for (int n = 0; n < 16; ++n) h[n] = 0.f;
    float sdsum = 0.f;
    __syncthreads();

    float xcur[8], xnxt[8];
#pragma unroll
    for (int s = 0; s < 8; ++s) xcur[s] = xcv[(long)s*DI_ + d];

    for (int g = 0; g < CL_; g += 8) {
        if (g + 8 < CL_) {
#pragma unroll
            for (int s = 0; s < 8; ++s) xnxt[s] = xcv[(long)(g+8+s)*DI_ + d];
        }
#pragma unroll
        for (int s = 0; s < 8; ++s) {
            const float* xrow = &sX[(g+s)*48];
            const float4 t0 = *(const float4*)&xrow[0];
            const float4 t1 = *(const float4*)&xrow[4];
            const float4 t2 = *(const float4*)&xrow[8];
            const float4 t3 = *(const float4*)&xrow[12];
            float acc = bias;
            acc = fmaf(t0.x,wreg[0],acc);  acc = fmaf(t0.y,wreg[1],acc);
            acc = fmaf(t0.z,wreg[2],acc);  acc = fmaf(t0.w,wreg[3],acc);
            acc = fmaf(t1.x,wreg[4],acc);  acc = fmaf(t1.y,wreg[5],acc);
            acc = fmaf(t1.z,wreg[6],acc);  acc = fmaf(t1.w,wreg[7],acc);
            acc = fmaf(t2.x,wreg[8],acc);  acc = fmaf(t2.y,wreg[9],acc);
            acc = fmaf(t2.z,wreg[10],acc); acc = fmaf(t2.w,wreg[11],acc);
            acc = fmaf(t3.x,wreg[12],acc); acc = fmaf(t3.y,wreg[13],acc);
            acc = fmaf(t3.z,wreg[14],acc); acc = fmaf(t3.w,wreg[15],acc);
            const float delta = softplus_fast(acc);
            const float tx = delta * xcur[s];
            sdsum += delta;
#pragma unroll
            for (int n4 = 0; n4 < 4; ++n4) {
                const float4 Bv = *(const float4*)&xrow[16 + n4*4];
                h[n4*4+0] = fmaf(exp2_fast(delta*a2[n4*4+0]), h[n4*4+0], tx*Bv.x);
                h[n4*4+1] = fmaf(exp2_fast(delta*a2[n4*4+1]), h[n4*4+1], tx*Bv.y);
                h[n4*4+2] = fmaf(exp2_fast(delta*a2[n4*4+2]), h[n4*4+2], tx*Bv.z);
                h[n4*4+3] = fmaf(exp2_fast(delta*a2[n4*4+3]), h[n4*4+3], tx*Bv.w);
            }
        }
#pragma unroll
        for (int s = 0; s < 8; ++s) xcur[s] = xnxt[s];
    }
    float* hb = hbuf + ((((long)v*B_ + b)*NC_ + c)*DI_ + d)*16;
#pragma unroll
    for (int n = 0; n < 16; n += 4) {
        float4 r; r.x = h[n]; r.y = h[n+1]; r.z = h[n+2]; r.w = h[n+3];
        *(float4*)&hb[n] = r;
    }
    sdel[(((long)v*B_ + b)*NC_ + c)*DI_ + d] = sdsum;
}

__global__ __launch_bounds__(256) void scanB(const float* __restrict__ A_log,
                                             const float* __restrict__ sdel,
                                             float* __restrict__ hbuf)
{
    const long lin = (long)blockIdx.x*256 + threadIdx.x;   /* 131072 = V*B*DI*DS */
    const int n = (int)(lin & 15);
    const int d = (int)((lin >> 4) & 511);
    const int b = (int)((lin >> 13) & 3);
    const int v = (int)(lin >> 15);
    const float a2 = -exp2_fast(A_log[((long)v*DI_ + d)*DS_ + n] * LOG2E) * LOG2E;
    float h = 0.f;
    long hidx = (((long)(v*B_ + b)*NC_)*DI_ + d)*16 + n;
    long sidx = ((long)(v*B_ + b)*NC_)*DI_ + d;
#pragma unroll
    for (int c = 0; c < NC_; ++c) {
        const float he = hbuf[hidx];
        const float P  = exp2_fast(a2 * sdel[sidx]);
        hbuf[hidx] = h;                 /* incoming state for chunk c */
        h = fmaf(P, h, he);
        hidx += (long)DI_*16;
        sidx += DI_;
    }
}

/* scanC: seeded local scan + skip + gate; writes y as separate bf16 hi/lo planes */
__global__ __launch_bounds__(256) void scanC(const float* __restrict__ xz,
                                             const float* __restrict__ xcin,
                                             const float* __restrict__ part,
                                             const float* __restrict__ A_log,
                                             const float* __restrict__ wdt,
                                             const float* __restrict__ bdt,
                                             const float* __restrict__ D_skip,
                                             const float* __restrict__ hbuf,
                                             ushort* __restrict__ yh,
                                             ushort* __restrict__ yl)
{
    const int c = blockIdx.x >> 1, half = blockIdx.x & 1;
    const int b = blockIdx.y, v = blockIdx.z;
    const int d = half*256 + threadIdx.x;
    const long rowbase = (long)v*ML + (long)b*L_ + (long)c*CL_;
    const float* xzv = xz   + rowbase*(2*DI_);
    const float* xcv = xcin + rowbase*DI_;
    const float* pv  = part + rowbase*192;
    ushort* yhv = yh + rowbase*DI_;
    ushort* ylv = yl + rowbase*DI_;

    __shared__ float sX[CL_*48];
    for (int t = threadIdx.x; t < CL_*48; t += 256) {
        const int row = t/48, j = t - row*48;
        const float* pr = pv + (long)row*192 + j;
        sX[t] = (pr[0] + pr[48]) + (pr[96] + pr[144]);
    }

    float a2[16];
#pragma unroll
    for (int n = 0; n < 16; ++n)
        a2[n] = -exp2_fast(A_log[((long)v*DI_ + d)*DS_ + n] * LOG2E) * LOG2E;
    float wreg[16];
    {
        const float* wp = wdt + ((long)v*DI_ + d)*DTR_;
#pragma unroll
        for (int r = 0; r < 16; r += 4) {
            const float4 t4 = *(const float4*)(wp + r);
            wreg[r]=t4.x; wreg[r+1]=t4.y; wreg[r+2]=t4.z; wreg[r+3]=t4.w;
        }
    }
    const float bias = bdt[(long)v*DI_ + d];
    const float dsk = D_skip[v*DI_ + d];
    float h[16];
    const float* hb = hbuf + ((((long)v*B_ + b)*NC_ + c)*DI_ + d)*16;
#pragma unroll
    for (int n = 0; n < 16; n += 4) {
        const float4 r = *(const float4*)&hb[n];
        h[n] = r.x; h[n+1] = r.y; h[n+2] = r.z; h[n+3] = r.w;
    }
    __syncthreads();

    float xcur[8], zcur[8], xnxt[8], znxt[8];
#pragma unroll
    for (int s = 0; s < 8; ++s) {
        xcur[s] = xcv[(long)s*DI_ + d];
        zcur[s] = xzv[(long)s*(2*DI_) + DI_ + d];
    }

    for (int g = 0; g < CL_; g += 8) {
        if (g + 8 < CL_) {
#pragma unroll
            for (int s = 0; s < 8; ++s) {
                xnxt[s] = xcv[(long)(g+8+s)*DI_ + d];
                znxt[s] = xzv[(long)(g+8+s)*(2*DI_) + DI_ + d];
            }
        }
#pragma unroll
        for (int s = 0; s < 8; ++s) {
            const float* xrow = &sX[(g+s)*48];
            const float4 t0 = *(const float4*)&xrow[0];
            const float4 t1 = *(const float4*)&xrow[4];
            const float4 t2 = *(const float4*)&xrow[8];
            const float4 t3 = *(const float4*)&xrow[12];
            float acc = bias;
            acc = fmaf(t0.x,wreg[0],acc);  acc = fmaf(t0.y,wreg[1],acc);
            acc = fmaf(t0.z,wreg[2],acc);  acc = fmaf(t0.w,wreg[3],acc);
            acc = fmaf(t1.x,wreg[4],acc);  acc = fmaf(t1.y,wreg[5],acc);
            acc = fmaf(t1.z,wreg[6],acc);  acc = fmaf(t1.w,wreg[7],acc);
            acc = fmaf(t2.x,wreg[8],acc);  acc = fmaf(t2.y,wreg[9],acc);
            acc = fmaf(t2.z,wreg[10],acc); acc = fmaf(t2.w,wreg[11],acc);
            acc = fmaf(t3.x,wreg[12],acc); acc = fmaf(t3.y,wreg[13],acc);
            acc = fmaf(t3.z,wreg[14],acc); acc = fmaf(t3.w,wreg[15],acc);
            const float delta = softplus_fast(acc);
            const float xcval = xcur[s];
            const float tx = delta * xcval;
            float ys = 0.f;
#pragma unroll
            for (int n4 = 0; n4 < 4; ++n4) {
                const float4 Bv = *(const float4*)&xrow[16 + n4*4];
                const float4 Cv = *(const float4*)&xrow[32 + n4*4];
                h[n4*4+0] = fmaf(exp2_fast(delta*a2[n4*4+0]), h[n4*4+0], tx*Bv.x);
                h[n4*4+1] = fmaf(exp2_fast(delta*a2[n4*4+1]), h[n4*4+1], tx*Bv.y);
                h[n4*4+2] = fmaf(exp2_fast(delta*a2[n4*4+2]), h[n4*4+2], tx*Bv.z);
                h[n4*4+3] = fmaf(exp2_fast(delta*a2[n4*4+3]), h[n4*4+3], tx*Bv.w);
                ys = fmaf(h[n4*4+0], Cv.x, ys);
                ys = fmaf(h[n4*4+1], Cv.y, ys);
                ys = fmaf(h[n4*4+2], Cv.z, ys);
                ys = fmaf(h[n4*4+3], Cv.w, ys);
            }
            float outv = ys + xcval * dsk;
            outv *= silu_fast(zcur[s]);
            const ushort hv = f2bf(outv);
            const ushort lv = f2bf(outv - bf2f(hv));
            yhv[(long)(g+s)*DI_ + d] = hv;
            ylv[(long)(g+s)*DI_ + d] = lv;
        }
#pragma unroll
        for (int s = 0; s < 8; ++s) { xcur[s] = xnxt[s]; zcur[s] = znxt[s]; }
    }
}

extern "C" void kernel_launch(void* const* d_in, const int* in_sizes, int n_in,
                              void* d_out, int out_size, void* d_ws, size_t ws_size,
                              hipStream_t stream)
{
    const float* x      = (const float*)d_in[0];
    const float* ln_g   = (const float*)d_in[1];
    const float* ln_b   = (const float*)d_in[2];
    const float* w_in   = (const float*)d_in[3];
    const float* conv_w = (const float*)d_in[4];
    const float* conv_b = (const float*)d_in[5];
    const float* w_x    = (const float*)d_in[6];
    const float* w_dt   = (const float*)d_in[7];
    const float* b_dt   = (const float*)d_in[8];
    const float* A_log  = (const float*)d_in[9];
    const float* D_skip = (const float*)d_in[10];
    const float* w_out  = (const float*)d_in[11];
    float* out = (float*)d_out;

    float* ws   = (float*)d_ws;
    float* xz   = ws + OFF_XZ;
    float* xc   = ws + OFF_XC;
    float* pbuf = ws + OFF_P;
    float* hbuf = ws + OFF_HB;
    float* sdel = ws + OFF_SDEL;

    ushort* xlnh = (ushort*)(ws + OFF_XLN);
    ushort* xlnl = xlnh + (long)V_*ML*D_;
    ushort* wih  = (ushort*)(ws + OFF_WIN);
    ushort* wil  = wih + (long)V_*(2*DI_)*D_;
    ushort* woh  = (ushort*)(ws + OFF_WOUT);
    ushort* wol  = woh + (long)V_*D_*DI_;
    ushort* yh   = (ushort*)(ws + OFF_Y);
    ushort* yl   = yh + (long)V_*ML*DI_;

    /* 1. weight splits (independent, up front) */
    split_w<<<dim3((V_*(2*DI_)*D_/4 + 255)/256), 256, 0, stream>>>(w_in, wih, wil, V_*(2*DI_)*D_/4);
    split_w<<<dim3((V_*D_*DI_/4 + 255)/256), 256, 0, stream>>>(w_out, woh, wol, V_*D_*DI_/4);

    /* 2. LayerNorm fused with hi/lo split */
    ln_split<<<dim3(ML, V_), 256, 0, stream>>>(x, ln_g, ln_b, xlnh, xlnl);

    /* 3. xz = xln @ w_in^T via direct-fragment-load split-bf16 MFMA */
    mfma_gemm_in<<<dim3((2*DI_)/128, ML/128, V_), 256, 0, stream>>>(xlnh, xlnl, wih, wil, xz);

    /* 4. depthwise causal conv + SiLU -> xc f32 */
    conv_silu<<<dim3(ML, V_), DI_, 0, stream>>>(xz, conv_w, conv_b, xc);

    /* 5. xdbl partials = xc @ w_x^T, split-K=4 -> pbuf (summed inside the scans) */
    gemm_nt48_sk<<<dim3(ML/64, 4, V_), 256, 0, stream>>>(xc, w_x, pbuf);

    /* 6. chunked parallel scan (NC=32), delta fused, partial-sum staged */
    scanA<<<dim3(NC_*2, B_, V_), 256, 0, stream>>>(xc, pbuf, A_log, w_dt, b_dt, hbuf, sdel);
    scanB<<<dim3((V_*B_*DI_*DS_)/256), 256, 0, stream>>>(A_log, sdel, hbuf);
    scanC<<<dim3(NC_*2, B_, V_), 256, 0, stream>>>(xz, xc, pbuf, A_log, w_dt, b_dt,
                                                   D_skip, hbuf, yh, yl);

    /* 7. out = y @ w_out^T via direct-fragment-load split-bf16 MFMA, scattered + dup */
    mfma_gemm_out<<<dim3(D_/128, ML/64, V_), 256, 0, stream>>>(yh, yl, woh, wol, out);
}